// Round 5
// baseline (14.165 us; speedup 1.0000x reference)
//
#include <hip/hip_runtime.h>
#include <hip/hip_bf16.h>
#include <math.h>

#define S 26
#define D 7
#define DA 11
#define V 29
#define NT 256

__device__ __forceinline__ float dot8(float4 a0, float4 a1, float4 b0, float4 b1) {
    return a0.x*b0.x + a0.y*b0.y + a0.z*b0.z + a0.w*b0.w
         + a1.x*b1.x + a1.y*b1.y + a1.z*b1.z + a1.w*b1.w;
}
__device__ __forceinline__ float dot12(float4 a0, float4 a1, float4 a2,
                                       float4 b0, float4 b1, float4 b2) {
    return a0.x*b0.x + a0.y*b0.y + a0.z*b0.z + a0.w*b0.w
         + a1.x*b1.x + a1.y*b1.y + a1.z*b1.z + a1.w*b1.w
         + a2.x*b2.x + a2.y*b2.y + a2.z*b2.z + a2.w*b2.w;
}

__global__ __launch_bounds__(NT) void transformer_fwd(
    const int* __restrict__ x,
    const float* __restrict__ emb_table,
    const float* __restrict__ pos,
    const float* __restrict__ w_k0, const float* __restrict__ b_k0,
    const float* __restrict__ w_q0, const float* __restrict__ b_q0,
    const float* __restrict__ w_v0, const float* __restrict__ b_v0,
    const float* __restrict__ w_f0, const float* __restrict__ b_f0,
    const float* __restrict__ w_k1, const float* __restrict__ b_k1,
    const float* __restrict__ w_q1, const float* __restrict__ b_q1,
    const float* __restrict__ w_v1, const float* __restrict__ b_v1,
    const float* __restrict__ w_f1, const float* __restrict__ b_f1,
    const float* __restrict__ w_out, const float* __restrict__ b_out,
    float* __restrict__ out)
{
    // LDS arena, all float4, zero-padded so every dot runs full width.
    __shared__ float4 wkv[2][12][2], wqv[2][12][2], wvv[2][12][2]; // [DA->12][D->8]
    __shared__ float4 wfv[2][8][3];                                // [D->8][DA->12]
    __shared__ float4 wov[32][2];                                  // [V->32][D->8]
    __shared__ float4 bkv[2][3], bqv[2][3], bvv[2][3], bfv[2][2];
    __shared__ float  bos[32];
    __shared__ float4 hv[S][2];          // h[26][8], col 7 == 0
    __shared__ float4 kkv[S][3];         // k[26][12], col 11 == 0
    __shared__ float4 qqv[S][3], vvv[S][3];

    const int t = threadIdx.x;

    // ================= PREFETCH (one batched latency exposure) =============
    {
        const int es = t >> 3, ed = t & 7;
        float hval = 0.f;
        if (t < S * 8) {
            if (ed < D) {
                const int xi = x[es];
                hval = emb_table[xi * D + ed] + pos[es * D + ed];
            }
            ((float*)hv)[t] = hval;
        }
        if (t < 96) {  // wk/wq/wv [12][8]
            const int r = t >> 3, c = t & 7;
            const bool v = (r < DA) && (c < D);
            const int idx = r * D + c;
            ((float*)wkv[0])[t] = v ? w_k0[idx] : 0.f;
            ((float*)wkv[1])[t] = v ? w_k1[idx] : 0.f;
            ((float*)wqv[0])[t] = v ? w_q0[idx] : 0.f;
            ((float*)wqv[1])[t] = v ? w_q1[idx] : 0.f;
            ((float*)wvv[0])[t] = v ? w_v0[idx] : 0.f;
            ((float*)wvv[1])[t] = v ? w_v1[idx] : 0.f;
            const int rf = t / 12, cf = t % 12;   // wf [8][12]
            const bool vf = (rf < D) && (cf < DA);
            const int idxf = rf * DA + cf;
            ((float*)wfv[0])[t] = vf ? w_f0[idxf] : 0.f;
            ((float*)wfv[1])[t] = vf ? w_f1[idxf] : 0.f;
        }
        {   // wo [32][8]
            const int r = t >> 3, c = t & 7;
            const bool v = (r < V) && (c < D);
            ((float*)wov)[t] = v ? w_out[r * D + c] : 0.f;
        }
        if (t < 12) {
            ((float*)bkv[0])[t] = (t < DA) ? b_k0[t] : 0.f;
            ((float*)bkv[1])[t] = (t < DA) ? b_k1[t] : 0.f;
            ((float*)bqv[0])[t] = (t < DA) ? b_q0[t] : 0.f;
            ((float*)bqv[1])[t] = (t < DA) ? b_q1[t] : 0.f;
            ((float*)bvv[0])[t] = (t < DA) ? b_v0[t] : 0.f;
            ((float*)bvv[1])[t] = (t < DA) ? b_v1[t] : 0.f;
        }
        if (t < 8) {
            ((float*)bfv[0])[t] = (t < D) ? b_f0[t] : 0.f;
            ((float*)bfv[1])[t] = (t < D) ? b_f1[t] : 0.f;
        }
        if (t < 32) bos[t] = (t < V) ? b_out[t] : 0.f;
    }
    __syncthreads();

    for (int blk = 0; blk < 2; ++blk) {
        // ---- kqv: 234 threads, one float4 of one projection row each -------
        if (t < 234) {
            const int type = t / 78, rem = t % 78;
            const int r = rem / 3, c4 = rem % 3;
            const float4* W = (type == 0) ? &wkv[blk][0][0]
                             : (type == 1) ? &wqv[blk][0][0] : &wvv[blk][0][0];
            const float4  bb = ((type == 0) ? bkv[blk] : (type == 1) ? bqv[blk] : bvv[blk])[c4];
            const float4 h0 = hv[r][0], h1 = hv[r][1];
            const int c0 = c4 * 4;
            float4 o;
            o.x = dot8(h0, h1, W[(c0 + 0) * 2], W[(c0 + 0) * 2 + 1]) + bb.x;
            o.y = dot8(h0, h1, W[(c0 + 1) * 2], W[(c0 + 1) * 2 + 1]) + bb.y;
            o.z = dot8(h0, h1, W[(c0 + 2) * 2], W[(c0 + 2) * 2 + 1]) + bb.z;
            o.w = dot8(h0, h1, W[(c0 + 3) * 2], W[(c0 + 3) * 2 + 1]) + bb.w;
            float4* DST = (type == 0) ? &kkv[r][c4] : (type == 1) ? &qqv[r][c4] : &vvv[r][c4];
            *DST = o;
        }
        __syncthreads();

        // ---- MEGA stage: att -> softmax -> res -> proj (-> out) fused ------
        // 2 lanes per row (cols 0-15 / 16-31); rows 0-12 on wave 0, 13-25 on
        // wave 1. Everything row-local stays in registers; pair combines via
        // shfl_xor(.,1) (DPP quad-perm, ~free).
        {
            const int w = t >> 6, lane = t & 63;
            const int pr = lane >> 1, half = lane & 1;
            const int r = w * 13 + pr;
            if (w < 2 && pr < 13) {
                const float4 q0 = qqv[r][0], q1 = qqv[r][1], q2 = qqv[r][2];
                const int cbase = half << 4;
                float p[16];
                float m = -INFINITY;
                #pragma unroll
                for (int jj = 0; jj < 16; ++jj) {
                    const int c = cbase + jj;
                    const int ck = (c > 25) ? 25 : c;        // clamped reads are masked below
                    const float d = dot12(q0, q1, q2, kkv[ck][0], kkv[ck][1], kkv[ck][2]);
                    p[jj] = (c <= r) ? d : -INFINITY;
                    m = fmaxf(m, p[jj]);
                }
                m = fmaxf(m, __shfl_xor(m, 1));              // row max (finite: col 0 valid)
                float sum = 0.f;
                #pragma unroll
                for (int jj = 0; jj < 16; ++jj) {
                    p[jj] = __expf(p[jj] - m);               // exp(-inf - m) = 0 exactly
                    sum += p[jj];
                }
                sum += __shfl_xor(sum, 1);
                const float inv = 1.f / sum;
                #pragma unroll
                for (int jj = 0; jj < 16; ++jj) p[jj] *= inv;

                if (blk == 1) {                               // final att -> global
                    #pragma unroll
                    for (int jj = 0; jj < 16; ++jj) {
                        const int c = cbase + jj;
                        if (c < S) out[S * V + r * S + c] = p[jj];
                    }
                }

                // res half: sum over this lane's cols
                float4 a0 = make_float4(0.f,0.f,0.f,0.f), a1 = a0, a2 = a0;
                #pragma unroll
                for (int jj = 0; jj < 16; ++jj) {
                    const int j = cbase + jj;
                    const int jv = (j > 25) ? 25 : j;        // p[jj]==0 for clamped/masked
                    const float aj = p[jj];
                    const float4 v0 = vvv[jv][0], v1 = vvv[jv][1], v2 = vvv[jv][2];
                    a0.x += aj*v0.x; a0.y += aj*v0.y; a0.z += aj*v0.z; a0.w += aj*v0.w;
                    a1.x += aj*v1.x; a1.y += aj*v1.y; a1.z += aj*v1.z; a1.w += aj*v1.w;
                    a2.x += aj*v2.x; a2.y += aj*v2.y; a2.z += aj*v2.z; a2.w += aj*v2.w;
                }
                // combine halves -> full res row in both lanes
                a0.x += __shfl_xor(a0.x, 1); a0.y += __shfl_xor(a0.y, 1);
                a0.z += __shfl_xor(a0.z, 1); a0.w += __shfl_xor(a0.w, 1);
                a1.x += __shfl_xor(a1.x, 1); a1.y += __shfl_xor(a1.y, 1);
                a1.z += __shfl_xor(a1.z, 1); a1.w += __shfl_xor(a1.w, 1);
                a2.x += __shfl_xor(a2.x, 1); a2.y += __shfl_xor(a2.y, 1);
                a2.z += __shfl_xor(a2.z, 1); a2.w += __shfl_xor(a2.w, 1);

                // proj: this lane's 4 h-columns
                const int c0 = half * 4;
                const float4 bb = bfv[blk][half];
                float4 h4;
                h4.x = dot12(a0,a1,a2, wfv[blk][c0+0][0], wfv[blk][c0+0][1], wfv[blk][c0+0][2]) + bb.x;
                h4.y = dot12(a0,a1,a2, wfv[blk][c0+1][0], wfv[blk][c0+1][1], wfv[blk][c0+1][2]) + bb.y;
                h4.z = dot12(a0,a1,a2, wfv[blk][c0+2][0], wfv[blk][c0+2][1], wfv[blk][c0+2][2]) + bb.z;
                h4.w = dot12(a0,a1,a2, wfv[blk][c0+3][0], wfv[blk][c0+3][1], wfv[blk][c0+3][2]) + bb.w;

                if (blk == 0) {
                    hv[r][half] = h4;                        // next block's kqv reads it
                } else {
                    // exchange halves -> full h row, then fused output GEMM
                    float4 oth;
                    oth.x = __shfl_xor(h4.x, 1); oth.y = __shfl_xor(h4.y, 1);
                    oth.z = __shfl_xor(h4.z, 1); oth.w = __shfl_xor(h4.w, 1);
                    const float4 hh0 = half ? oth : h4;
                    const float4 hh1 = half ? h4 : oth;
                    #pragma unroll
                    for (int jj = 0; jj < 16; ++jj) {
                        const int c = cbase + jj;            // 0..31, wov/bos padded to 32
                        const float d = dot8(hh0, hh1, wov[c][0], wov[c][1]) + bos[c];
                        if (c < V) out[r * V + c] = d;
                    }
                }
            }
        }
        if (blk == 0) __syncthreads();
    }
}

extern "C" void kernel_launch(void* const* d_in, const int* in_sizes, int n_in,
                              void* d_out, int out_size, void* d_ws, size_t ws_size,
                              hipStream_t stream) {
    const int*   x         = (const int*)  d_in[0];
    const float* emb_table = (const float*)d_in[1];
    const float* pos       = (const float*)d_in[2];
    const float* w_k0 = (const float*)d_in[3];  const float* b_k0 = (const float*)d_in[4];
    const float* w_q0 = (const float*)d_in[5];  const float* b_q0 = (const float*)d_in[6];
    const float* w_v0 = (const float*)d_in[7];  const float* b_v0 = (const float*)d_in[8];
    const float* w_f0 = (const float*)d_in[9];  const float* b_f0 = (const float*)d_in[10];
    const float* w_k1 = (const float*)d_in[11]; const float* b_k1 = (const float*)d_in[12];
    const float* w_q1 = (const float*)d_in[13]; const float* b_q1 = (const float*)d_in[14];
    const float* w_v1 = (const float*)d_in[15]; const float* b_v1 = (const float*)d_in[16];
    const float* w_f1 = (const float*)d_in[17]; const float* b_f1 = (const float*)d_in[18];
    const float* w_out = (const float*)d_in[19]; const float* b_out = (const float*)d_in[20];
    float* out = (float*)d_out;

    transformer_fwd<<<1, NT, 0, stream>>>(
        x, emb_table, pos,
        w_k0, b_k0, w_q0, b_q0, w_v0, b_v0, w_f0, b_f0,
        w_k1, b_k1, w_q1, b_q1, w_v1, b_v1, w_f1, b_f1,
        w_out, b_out, out);
}

// Round 6
// 11.048 us; speedup vs baseline: 1.2822x; 1.2822x over previous
//
#include <hip/hip_runtime.h>
#include <hip/hip_bf16.h>
#include <math.h>

#define S 26
#define D 7
#define DA 11
#define V 29
#define NT 256

__device__ __forceinline__ float dot8(float4 a0, float4 a1, float4 b0, float4 b1) {
    return a0.x*b0.x + a0.y*b0.y + a0.z*b0.z + a0.w*b0.w
         + a1.x*b1.x + a1.y*b1.y + a1.z*b1.z + a1.w*b1.w;
}
__device__ __forceinline__ float dot12(float4 a0, float4 a1, float4 a2,
                                       float4 b0, float4 b1, float4 b2) {
    return a0.x*b0.x + a0.y*b0.y + a0.z*b0.z + a0.w*b0.w
         + a1.x*b1.x + a1.y*b1.y + a1.z*b1.z + a1.w*b1.w
         + a2.x*b2.x + a2.y*b2.y + a2.z*b2.z + a2.w*b2.w;
}

__global__ __launch_bounds__(NT) void transformer_fwd(
    const int* __restrict__ x,
    const float* __restrict__ emb_table,
    const float* __restrict__ pos,
    const float* __restrict__ w_k0, const float* __restrict__ b_k0,
    const float* __restrict__ w_q0, const float* __restrict__ b_q0,
    const float* __restrict__ w_v0, const float* __restrict__ b_v0,
    const float* __restrict__ w_f0, const float* __restrict__ b_f0,
    const float* __restrict__ w_k1, const float* __restrict__ b_k1,
    const float* __restrict__ w_q1, const float* __restrict__ b_q1,
    const float* __restrict__ w_v1, const float* __restrict__ b_v1,
    const float* __restrict__ w_f1, const float* __restrict__ b_f1,
    const float* __restrict__ w_out, const float* __restrict__ b_out,
    float* __restrict__ out)
{
    // LDS arena, float4, zero-padded so every dot runs full width.
    __shared__ float4 wkv[2][12][2], wqv[2][12][2], wvv[2][12][2]; // [DA->12][D->8]
    __shared__ float4 wfv[2][8][3];                                // [D->8][DA->12]
    __shared__ float4 wov[32][2];                                  // [V->32][D->8]
    __shared__ float4 bkv[2][3], bqv[2][3], bvv[2][3];
    __shared__ float  bfs[2][8];
    __shared__ float  bos[32];
    __shared__ float4 hv[S][2];          // h[26][8], col 7 == 0
    __shared__ float4 kkv[32][3];        // k[32][12]; rows 26..31 & col 11 == 0
    __shared__ float4 qqv[S][3];
    __shared__ float4 vvv[32][3];        // v[32][12]; rows 26..31 zero

    const int t = threadIdx.x;

    // ================= PREFETCH (one batched latency exposure) =============
    {
        const int es = t >> 3, ed = t & 7;
        float hval = 0.f;
        if (t < S * 8) {
            if (ed < D) {
                const int xi = x[es];
                hval = emb_table[xi * D + ed] + pos[es * D + ed];
            }
            ((float*)hv)[t] = hval;
        }
        if (t < 96) {  // wk/wq/wv [12][8]
            const int r = t >> 3, c = t & 7;
            const bool v = (r < DA) && (c < D);
            const int idx = r * D + c;
            ((float*)wkv[0])[t] = v ? w_k0[idx] : 0.f;
            ((float*)wkv[1])[t] = v ? w_k1[idx] : 0.f;
            ((float*)wqv[0])[t] = v ? w_q0[idx] : 0.f;
            ((float*)wqv[1])[t] = v ? w_q1[idx] : 0.f;
            ((float*)wvv[0])[t] = v ? w_v0[idx] : 0.f;
            ((float*)wvv[1])[t] = v ? w_v1[idx] : 0.f;
            const int rf = t / 12, cf = t % 12;   // wf [8][12]
            const bool vf = (rf < D) && (cf < DA);
            const int idxf = rf * DA + cf;
            ((float*)wfv[0])[t] = vf ? w_f0[idxf] : 0.f;
            ((float*)wfv[1])[t] = vf ? w_f1[idxf] : 0.f;
        }
        {   // wo [32][8]
            const int r = t >> 3, c = t & 7;
            const bool v = (r < V) && (c < D);
            ((float*)wov)[t] = v ? w_out[r * D + c] : 0.f;
        }
        if (t < 12) {
            ((float*)bkv[0])[t] = (t < DA) ? b_k0[t] : 0.f;
            ((float*)bkv[1])[t] = (t < DA) ? b_k1[t] : 0.f;
            ((float*)bqv[0])[t] = (t < DA) ? b_q0[t] : 0.f;
            ((float*)bqv[1])[t] = (t < DA) ? b_q1[t] : 0.f;
            ((float*)bvv[0])[t] = (t < DA) ? b_v0[t] : 0.f;
            ((float*)bvv[1])[t] = (t < DA) ? b_v1[t] : 0.f;
        }
        if (t < 8) {
            bfs[0][t] = (t < D) ? b_f0[t] : 0.f;
            bfs[1][t] = (t < D) ? b_f1[t] : 0.f;
        }
        if (t < 32) bos[t] = (t < V) ? b_out[t] : 0.f;
        if (t < 72) {  // zero pad rows 26..31 of kkv and vvv (72 floats each)
            ((float*)kkv)[26 * 12 + t] = 0.f;
            ((float*)vvv)[26 * 12 + t] = 0.f;
        }
    }
    __syncthreads();

    for (int blk = 0; blk < 2; ++blk) {
        // ---- kqv: 234 threads, one float4 of one projection row each -------
        if (t < 234) {
            const int type = t / 78, rem = t % 78;
            const int r = rem / 3, c4 = rem % 3;
            const float4* W = (type == 0) ? &wkv[blk][0][0]
                             : (type == 1) ? &wqv[blk][0][0] : &wvv[blk][0][0];
            const float4  bb = ((type == 0) ? bkv[blk] : (type == 1) ? bqv[blk] : bvv[blk])[c4];
            const float4 h0 = hv[r][0], h1 = hv[r][1];
            const int c0 = c4 * 4;
            float4 o;
            o.x = dot8(h0, h1, W[(c0 + 0) * 2], W[(c0 + 0) * 2 + 1]) + bb.x;
            o.y = dot8(h0, h1, W[(c0 + 1) * 2], W[(c0 + 1) * 2 + 1]) + bb.y;
            o.z = dot8(h0, h1, W[(c0 + 2) * 2], W[(c0 + 2) * 2 + 1]) + bb.z;
            o.w = dot8(h0, h1, W[(c0 + 3) * 2], W[(c0 + 3) * 2 + 1]) + bb.w;
            float4* DST = (type == 0) ? &kkv[r][c4] : (type == 1) ? &qqv[r][c4] : &vvv[r][c4];
            *DST = o;
        }
        __syncthreads();

        // ---- FUSED att -> softmax -> res -> proj (-> out), 8 lanes/row -----
        // Row r owns lanes r*8..r*8+7 (8 divides 64: no wave straddle).
        // Lane g covers cols 4g..4g+3. Row reductions: shfl_xor 1/2/4.
        if (t < S * 8) {
            const int r = t >> 3, g = t & 7;
            const int cbase = g << 2;
            const float4 q0 = qqv[r][0], q1 = qqv[r][1], q2 = qqv[r][2];

            float p[4];
            float m = -INFINITY;
            #pragma unroll
            for (int jj = 0; jj < 4; ++jj) {
                const int c = cbase + jj;                     // kkv padded to 32 rows
                const float d = dot12(q0, q1, q2, kkv[c][0], kkv[c][1], kkv[c][2]);
                p[jj] = (c <= r) ? d : -INFINITY;
                m = fmaxf(m, p[jj]);
            }
            m = fmaxf(m, __shfl_xor(m, 1));
            m = fmaxf(m, __shfl_xor(m, 2));
            m = fmaxf(m, __shfl_xor(m, 4));                   // finite: col0 valid

            float sum = 0.f;
            #pragma unroll
            for (int jj = 0; jj < 4; ++jj) {
                p[jj] = __expf(p[jj] - m);                    // exp(-inf - m) = 0
                sum += p[jj];
            }
            sum += __shfl_xor(sum, 1);
            sum += __shfl_xor(sum, 2);
            sum += __shfl_xor(sum, 4);
            const float inv = 1.f / sum;
            #pragma unroll
            for (int jj = 0; jj < 4; ++jj) p[jj] *= inv;

            if (blk == 1) {                                   // final att -> global
                #pragma unroll
                for (int jj = 0; jj < 4; ++jj) {
                    const int c = cbase + jj;
                    if (c < S) out[S * V + r * S + c] = p[jj];
                }
            }

            // res partial over this lane's 4 cols (vvv padded: rows >25 zero)
            float4 a0 = make_float4(0.f,0.f,0.f,0.f), a1 = a0, a2 = a0;
            #pragma unroll
            for (int jj = 0; jj < 4; ++jj) {
                const int j = cbase + jj;
                const float aj = p[jj];
                const float4 v0 = vvv[j][0], v1 = vvv[j][1], v2 = vvv[j][2];
                a0.x += aj*v0.x; a0.y += aj*v0.y; a0.z += aj*v0.z; a0.w += aj*v0.w;
                a1.x += aj*v1.x; a1.y += aj*v1.y; a1.z += aj*v1.z; a1.w += aj*v1.w;
                a2.x += aj*v2.x; a2.y += aj*v2.y; a2.z += aj*v2.z; a2.w += aj*v2.w;
            }
            #pragma unroll
            for (int mask = 1; mask <= 4; mask <<= 1) {
                a0.x += __shfl_xor(a0.x, mask); a0.y += __shfl_xor(a0.y, mask);
                a0.z += __shfl_xor(a0.z, mask); a0.w += __shfl_xor(a0.w, mask);
                a1.x += __shfl_xor(a1.x, mask); a1.y += __shfl_xor(a1.y, mask);
                a1.z += __shfl_xor(a1.z, mask); a1.w += __shfl_xor(a1.w, mask);
                a2.x += __shfl_xor(a2.x, mask); a2.y += __shfl_xor(a2.y, mask);
                a2.z += __shfl_xor(a2.z, mask); a2.w += __shfl_xor(a2.w, mask);
            }

            // proj: lane g computes h[r][g]  (g==7 pad col -> bfs pad 0)
            const float hcol = dot12(a0, a1, a2,
                                     wfv[blk][g][0], wfv[blk][g][1], wfv[blk][g][2])
                             + bfs[blk][g];

            if (blk == 0) {
                ((float*)hv)[(r << 3) + g] = hcol;            // conflict-free b32
            } else {
                // gather full h row via shfl, then fused output GEMM
                const int rowlane = (t & 63) & ~7;
                float hh[8];
                #pragma unroll
                for (int d = 0; d < 8; ++d) hh[d] = __shfl(hcol, rowlane + d, 64);
                const float4 hh0 = make_float4(hh[0], hh[1], hh[2], hh[3]);
                const float4 hh1 = make_float4(hh[4], hh[5], hh[6], hh[7]);
                #pragma unroll
                for (int jj = 0; jj < 4; ++jj) {
                    const int c = cbase + jj;                 // wov/bos padded to 32
                    const float d = dot8(hh0, hh1, wov[c][0], wov[c][1]) + bos[c];
                    if (c < V) out[r * V + c] = d;
                }
            }
        }
        if (blk == 0) __syncthreads();                        // hv ready for blk1 kqv
    }
}

extern "C" void kernel_launch(void* const* d_in, const int* in_sizes, int n_in,
                              void* d_out, int out_size, void* d_ws, size_t ws_size,
                              hipStream_t stream) {
    const int*   x         = (const int*)  d_in[0];
    const float* emb_table = (const float*)d_in[1];
    const float* pos       = (const float*)d_in[2];
    const float* w_k0 = (const float*)d_in[3];  const float* b_k0 = (const float*)d_in[4];
    const float* w_q0 = (const float*)d_in[5];  const float* b_q0 = (const float*)d_in[6];
    const float* w_v0 = (const float*)d_in[7];  const float* b_v0 = (const float*)d_in[8];
    const float* w_f0 = (const float*)d_in[9];  const float* b_f0 = (const float*)d_in[10];
    const float* w_k1 = (const float*)d_in[11]; const float* b_k1 = (const float*)d_in[12];
    const float* w_q1 = (const float*)d_in[13]; const float* b_q1 = (const float*)d_in[14];
    const float* w_v1 = (const float*)d_in[15]; const float* b_v1 = (const float*)d_in[16];
    const float* w_f1 = (const float*)d_in[17]; const float* b_f1 = (const float*)d_in[18];
    const float* w_out = (const float*)d_in[19]; const float* b_out = (const float*)d_in[20];
    float* out = (float*)d_out;

    transformer_fwd<<<1, NT, 0, stream>>>(
        x, emb_table, pos,
        w_k0, b_k0, w_q0, b_q0, w_v0, b_v0, w_f0, b_f0,
        w_k1, b_k1, w_q1, b_q1, w_v1, b_v1, w_f1, b_f1,
        w_out, b_out, out);
}

// Round 7
// 11.028 us; speedup vs baseline: 1.2845x; 1.0018x over previous
//
#include <hip/hip_runtime.h>
#include <hip/hip_bf16.h>
#include <math.h>

#define S 26
#define D 7
#define DA 11
#define V 29
#define NT 256

__device__ __forceinline__ float dot8(float4 a0, float4 a1, float4 b0, float4 b1) {
    return a0.x*b0.x + a0.y*b0.y + a0.z*b0.z + a0.w*b0.w
         + a1.x*b1.x + a1.y*b1.y + a1.z*b1.z + a1.w*b1.w;
}
__device__ __forceinline__ float dot12(float4 a0, float4 a1, float4 a2,
                                       float4 b0, float4 b1, float4 b2) {
    return a0.x*b0.x + a0.y*b0.y + a0.z*b0.z + a0.w*b0.w
         + a1.x*b1.x + a1.y*b1.y + a1.z*b1.z + a1.w*b1.w
         + a2.x*b2.x + a2.y*b2.y + a2.z*b2.z + a2.w*b2.w;
}

__global__ __launch_bounds__(NT) void transformer_fwd(
    const int* __restrict__ x,
    const float* __restrict__ emb_table,
    const float* __restrict__ pos,
    const float* __restrict__ w_k0, const float* __restrict__ b_k0,
    const float* __restrict__ w_q0, const float* __restrict__ b_q0,
    const float* __restrict__ w_v0, const float* __restrict__ b_v0,
    const float* __restrict__ w_f0, const float* __restrict__ b_f0,
    const float* __restrict__ w_k1, const float* __restrict__ b_k1,
    const float* __restrict__ w_q1, const float* __restrict__ b_q1,
    const float* __restrict__ w_v1, const float* __restrict__ b_v1,
    const float* __restrict__ w_f1, const float* __restrict__ b_f1,
    const float* __restrict__ w_out, const float* __restrict__ b_out,
    float* __restrict__ out)
{
    // LDS arena, float4, zero-padded so every dot runs full width.
    __shared__ float4 wkv[2][12][2], wqv[2][12][2], wvv[2][12][2]; // [DA->12][D->8]
    __shared__ float4 wfv[2][8][3];                                // [D->8][DA->12]
    __shared__ float4 wov[32][2];                                  // [V->32][D->8]
    __shared__ float4 bkv[2][3], bqv[2][3], bvv[2][3];
    __shared__ float  bfs[2][8];
    __shared__ float  bos[32];
    __shared__ float4 hv[S][2];          // h[26][8], col 7 == 0
    __shared__ float4 kkv[32][3];        // k[32][12]; rows 26..31 & col 11 == 0
    __shared__ float4 qqv[S][3];
    __shared__ float4 vvv[32][3];        // v[32][12]; rows 26..31 zero

    const int t = threadIdx.x;

    // ================= PREFETCH (one batched latency exposure) =============
    {
        const int es = t >> 3, ed = t & 7;
        float hval = 0.f;
        if (t < S * 8) {
            if (ed < D) {
                const int xi = x[es];
                hval = emb_table[xi * D + ed] + pos[es * D + ed];
            }
            ((float*)hv)[t] = hval;
        }
        if (t < 96) {  // wk/wq/wv [12][8]
            const int r = t >> 3, c = t & 7;
            const bool v = (r < DA) && (c < D);
            const int idx = r * D + c;
            ((float*)wkv[0])[t] = v ? w_k0[idx] : 0.f;
            ((float*)wkv[1])[t] = v ? w_k1[idx] : 0.f;
            ((float*)wqv[0])[t] = v ? w_q0[idx] : 0.f;
            ((float*)wqv[1])[t] = v ? w_q1[idx] : 0.f;
            ((float*)wvv[0])[t] = v ? w_v0[idx] : 0.f;
            ((float*)wvv[1])[t] = v ? w_v1[idx] : 0.f;
            const int rf = t / 12, cf = t % 12;   // wf [8][12]
            const bool vf = (rf < D) && (cf < DA);
            const int idxf = rf * DA + cf;
            ((float*)wfv[0])[t] = vf ? w_f0[idxf] : 0.f;
            ((float*)wfv[1])[t] = vf ? w_f1[idxf] : 0.f;
        }
        {   // wo [32][8]
            const int r = t >> 3, c = t & 7;
            const bool v = (r < V) && (c < D);
            ((float*)wov)[t] = v ? w_out[r * D + c] : 0.f;
        }
        if (t < 12) {
            ((float*)bkv[0])[t] = (t < DA) ? b_k0[t] : 0.f;
            ((float*)bkv[1])[t] = (t < DA) ? b_k1[t] : 0.f;
            ((float*)bqv[0])[t] = (t < DA) ? b_q0[t] : 0.f;
            ((float*)bqv[1])[t] = (t < DA) ? b_q1[t] : 0.f;
            ((float*)bvv[0])[t] = (t < DA) ? b_v0[t] : 0.f;
            ((float*)bvv[1])[t] = (t < DA) ? b_v1[t] : 0.f;
        }
        if (t < 8) {
            bfs[0][t] = (t < D) ? b_f0[t] : 0.f;
            bfs[1][t] = (t < D) ? b_f1[t] : 0.f;
        }
        if (t < 32) bos[t] = (t < V) ? b_out[t] : 0.f;
        if (t < 72) {  // zero pad rows 26..31 of kkv and vvv (72 floats each)
            ((float*)kkv)[26 * 12 + t] = 0.f;
            ((float*)vvv)[26 * 12 + t] = 0.f;
        }
    }
    __syncthreads();

    for (int blk = 0; blk < 2; ++blk) {
        // ---- kqv: 234 threads, one float4 of one projection row each -------
        if (t < 234) {
            const int type = t / 78, rem = t % 78;
            const int r = rem / 3, c4 = rem % 3;
            const float4* W = (type == 0) ? &wkv[blk][0][0]
                             : (type == 1) ? &wqv[blk][0][0] : &wvv[blk][0][0];
            const float4  bb = ((type == 0) ? bkv[blk] : (type == 1) ? bqv[blk] : bvv[blk])[c4];
            const float4 h0 = hv[r][0], h1 = hv[r][1];
            const int c0 = c4 * 4;
            float4 o;
            o.x = dot8(h0, h1, W[(c0 + 0) * 2], W[(c0 + 0) * 2 + 1]) + bb.x;
            o.y = dot8(h0, h1, W[(c0 + 1) * 2], W[(c0 + 1) * 2 + 1]) + bb.y;
            o.z = dot8(h0, h1, W[(c0 + 2) * 2], W[(c0 + 2) * 2 + 1]) + bb.z;
            o.w = dot8(h0, h1, W[(c0 + 3) * 2], W[(c0 + 3) * 2 + 1]) + bb.w;
            float4* DST = (type == 0) ? &kkv[r][c4] : (type == 1) ? &qqv[r][c4] : &vvv[r][c4];
            *DST = o;
        }
        __syncthreads();

        // ---- FUSED att -> softmax -> res -> proj (-> out), 8 lanes/row -----
        // Row r owns lanes r*8..r*8+7. Lane g covers cols 4g..4g+3.
        // Scalar reductions: shfl_xor 1/2/4. Vector res reduction: only
        // masks 1,2 (DPP-cheap), then PAIRED PROJ — lanes g and g^4 compute
        // dot12 of their quad-partial res with the SAME two wf columns
        // (cA=g&3, cB=cA+4) and combine with one scalar shfl_xor(.,4) each,
        // replacing 12 vector-wide mask-4 shuffles (LDS-pipe) per lane.
        if (t < S * 8) {
            const int r = t >> 3, g = t & 7;
            const int cbase = g << 2;
            const float4 q0 = qqv[r][0], q1 = qqv[r][1], q2 = qqv[r][2];

            float p[4];
            float m = -INFINITY;
            #pragma unroll
            for (int jj = 0; jj < 4; ++jj) {
                const int c = cbase + jj;                     // kkv padded to 32 rows
                const float d = dot12(q0, q1, q2, kkv[c][0], kkv[c][1], kkv[c][2]);
                p[jj] = (c <= r) ? d : -INFINITY;
                m = fmaxf(m, p[jj]);
            }
            m = fmaxf(m, __shfl_xor(m, 1));
            m = fmaxf(m, __shfl_xor(m, 2));
            m = fmaxf(m, __shfl_xor(m, 4));                   // finite: col0 valid

            float sum = 0.f;
            #pragma unroll
            for (int jj = 0; jj < 4; ++jj) {
                p[jj] = __expf(p[jj] - m);                    // exp(-inf - m) = 0
                sum += p[jj];
            }
            sum += __shfl_xor(sum, 1);
            sum += __shfl_xor(sum, 2);
            sum += __shfl_xor(sum, 4);
            const float inv = 1.f / sum;
            #pragma unroll
            for (int jj = 0; jj < 4; ++jj) p[jj] *= inv;

            if (blk == 1) {                                   // final att -> global
                #pragma unroll
                for (int jj = 0; jj < 4; ++jj) {
                    const int c = cbase + jj;
                    if (c < S) out[S * V + r * S + c] = p[jj];
                }
            }

            // res partial over this lane's 4 cols (vvv padded: rows >25 zero)
            float4 a0 = make_float4(0.f,0.f,0.f,0.f), a1 = a0, a2 = a0;
            #pragma unroll
            for (int jj = 0; jj < 4; ++jj) {
                const int j = cbase + jj;
                const float aj = p[jj];
                const float4 v0 = vvv[j][0], v1 = vvv[j][1], v2 = vvv[j][2];
                a0.x += aj*v0.x; a0.y += aj*v0.y; a0.z += aj*v0.z; a0.w += aj*v0.w;
                a1.x += aj*v1.x; a1.y += aj*v1.y; a1.z += aj*v1.z; a1.w += aj*v1.w;
                a2.x += aj*v2.x; a2.y += aj*v2.y; a2.z += aj*v2.z; a2.w += aj*v2.w;
            }
            // reduce within quad only (masks 1,2 -> DPP quad-perm)
            #pragma unroll
            for (int mask = 1; mask <= 2; mask <<= 1) {
                a0.x += __shfl_xor(a0.x, mask); a0.y += __shfl_xor(a0.y, mask);
                a0.z += __shfl_xor(a0.z, mask); a0.w += __shfl_xor(a0.w, mask);
                a1.x += __shfl_xor(a1.x, mask); a1.y += __shfl_xor(a1.y, mask);
                a1.z += __shfl_xor(a1.z, mask); a1.w += __shfl_xor(a1.w, mask);
                a2.x += __shfl_xor(a2.x, mask); a2.y += __shfl_xor(a2.y, mask);
                a2.z += __shfl_xor(a2.z, mask); a2.w += __shfl_xor(a2.w, mask);
            }
            // paired projection: g and g^4 (opposite quads) both compute
            // columns cA=g&3 and cB=cA+4; one scalar xor4 completes each dot.
            const int cA = g & 3, cB = cA + 4;
            float s0 = dot12(a0, a1, a2, wfv[blk][cA][0], wfv[blk][cA][1], wfv[blk][cA][2]);
            float s1 = dot12(a0, a1, a2, wfv[blk][cB][0], wfv[blk][cB][1], wfv[blk][cB][2]);
            s0 += __shfl_xor(s0, 4);
            s1 += __shfl_xor(s1, 4);
            const float hcol = ((g & 4) ? s1 : s0) + bfs[blk][g];   // == h[r][g]

            if (blk == 0) {
                ((float*)hv)[(r << 3) + g] = hcol;            // conflict-free b32
            } else {
                // gather full h row via shfl, then fused output GEMM
                const int rowlane = (t & 63) & ~7;
                float hh[8];
                #pragma unroll
                for (int d = 0; d < 8; ++d) hh[d] = __shfl(hcol, rowlane + d, 64);
                const float4 hh0 = make_float4(hh[0], hh[1], hh[2], hh[3]);
                const float4 hh1 = make_float4(hh[4], hh[5], hh[6], hh[7]);
                #pragma unroll
                for (int jj = 0; jj < 4; ++jj) {
                    const int c = cbase + jj;                 // wov/bos padded to 32
                    const float d = dot8(hh0, hh1, wov[c][0], wov[c][1]) + bos[c];
                    if (c < V) out[r * V + c] = d;
                }
            }
        }
        if (blk == 0) __syncthreads();                        // hv ready for blk1 kqv
    }
}

extern "C" void kernel_launch(void* const* d_in, const int* in_sizes, int n_in,
                              void* d_out, int out_size, void* d_ws, size_t ws_size,
                              hipStream_t stream) {
    const int*   x         = (const int*)  d_in[0];
    const float* emb_table = (const float*)d_in[1];
    const float* pos       = (const float*)d_in[2];
    const float* w_k0 = (const float*)d_in[3];  const float* b_k0 = (const float*)d_in[4];
    const float* w_q0 = (const float*)d_in[5];  const float* b_q0 = (const float*)d_in[6];
    const float* w_v0 = (const float*)d_in[7];  const float* b_v0 = (const float*)d_in[8];
    const float* w_f0 = (const float*)d_in[9];  const float* b_f0 = (const float*)d_in[10];
    const float* w_k1 = (const float*)d_in[11]; const float* b_k1 = (const float*)d_in[12];
    const float* w_q1 = (const float*)d_in[13]; const float* b_q1 = (const float*)d_in[14];
    const float* w_v1 = (const float*)d_in[15]; const float* b_v1 = (const float*)d_in[16];
    const float* w_f1 = (const float*)d_in[17]; const float* b_f1 = (const float*)d_in[18];
    const float* w_out = (const float*)d_in[19]; const float* b_out = (const float*)d_in[20];
    float* out = (float*)d_out;

    transformer_fwd<<<1, NT, 0, stream>>>(
        x, emb_table, pos,
        w_k0, b_k0, w_q0, b_q0, w_v0, b_v0, w_f0, b_f0,
        w_k1, b_k1, w_q1, b_q1, w_v1, b_v1, w_f1, b_f1,
        w_out, b_out, out);
}